// Round 2
// 682.559 us; speedup vs baseline: 1.0509x; 1.0509x over previous
//
#include <hip/hip_runtime.h>

#define N_BINS 15
#define GRID_MAIN 2048
#define BLOCK 256
#define ROWS_PER_GRP 4   // rows per 16-lane group per iteration (MLP unroll)

typedef float f32x4 __attribute__((ext_vector_type(4)));

// C = 128 floats = 512 B/row. A 16-lane group owns a row: lane `sub` holds
// cols [4*sub, 4*sub+3] and [64+4*sub, 64+4*sub+3] via two coalesced 16B
// loads (each load instr covers 256 B contiguous per row). Reduction trees are
// 4 steps (16 lanes), and each wave-level shuffle serves 4 rows at once.
__global__ __launch_bounds__(BLOCK) void ece_main(const float* __restrict__ logits,
                                                  const int* __restrict__ labels,
                                                  float* __restrict__ partial, // [3*N_BINS * nBlocks]
                                                  int N, int nBlocks) {
    __shared__ float s_acc[3 * N_BINS];
    const int tid = threadIdx.x;
    if (tid < 3 * N_BINS) s_acc[tid] = 0.f;
    __syncthreads();

    const int grp = tid >> 4;   // group id in block: 0..15
    const int sub = tid & 15;   // lane within 16-lane group

    auto process = [&](const f32x4 a, const f32x4 b, int lab, int row) {
        // local max + first-index argmax over this lane's 8 elements
        const int i0 = sub * 4, i1 = 64 + sub * 4;
        float m = a[0]; int mi = i0;
        if (a[1] > m) { m = a[1]; mi = i0 + 1; }
        if (a[2] > m) { m = a[2]; mi = i0 + 2; }
        if (a[3] > m) { m = a[3]; mi = i0 + 3; }
        if (b[0] > m) { m = b[0]; mi = i1; }
        if (b[1] > m) { m = b[1]; mi = i1 + 1; }
        if (b[2] > m) { m = b[2]; mi = i1 + 2; }
        if (b[3] > m) { m = b[3]; mi = i1 + 3; }
        #pragma unroll
        for (int off = 8; off > 0; off >>= 1) {   // stays within the 16-lane group
            float om = __shfl_xor(m, off);
            int   oi = __shfl_xor(mi, off);
            if (om > m || (om == m && oi < mi)) { m = om; mi = oi; }
        }
        float s = __expf(a[0] - m) + __expf(a[1] - m) + __expf(a[2] - m) + __expf(a[3] - m)
                + __expf(b[0] - m) + __expf(b[1] - m) + __expf(b[2] - m) + __expf(b[3] - m);
        #pragma unroll
        for (int off = 8; off > 0; off >>= 1)
            s += __shfl_xor(s, off);
        if (sub == 0) {
            const float conf = 1.0f / s;           // exp(m-m)/sum = max prob
            int bin = (int)ceilf(conf * (float)N_BINS) - 1;
            bin = min(max(bin, 0), N_BINS - 1);
            const float acc = (mi == lab) ? 1.0f : 0.0f;
            atomicAdd(&s_acc[bin],              1.0f);
            atomicAdd(&s_acc[N_BINS + bin],     conf);
            atomicAdd(&s_acc[2 * N_BINS + bin], acc);
        }
    };

    const int rowsPerIter = (BLOCK >> 4) * ROWS_PER_GRP;  // 64 rows per block-iteration
    const int rowStride   = nBlocks * rowsPerIter;

    for (int tile = blockIdx.x * rowsPerIter; tile < N; tile += rowStride) {
        const int base = tile + grp * ROWS_PER_GRP;
        if (tile + rowsPerIter <= N) {
            // fast path: all rows valid -> unconditional loads, 8 in flight/lane
            f32x4 va[ROWS_PER_GRP], vb[ROWS_PER_GRP];
            int   lab[ROWS_PER_GRP];
            #pragma unroll
            for (int j = 0; j < ROWS_PER_GRP; ++j) {
                const f32x4* rp = (const f32x4*)(logits + (size_t)(base + j) * 128);
                va[j]  = __builtin_nontemporal_load(rp + sub);
                vb[j]  = __builtin_nontemporal_load(rp + 16 + sub);
                lab[j] = labels[base + j];   // prefetched off the atomic critical path
            }
            #pragma unroll
            for (int j = 0; j < ROWS_PER_GRP; ++j)
                process(va[j], vb[j], lab[j], base + j);
        } else {
            #pragma unroll
            for (int j = 0; j < ROWS_PER_GRP; ++j) {
                if (base + j < N) {
                    const f32x4* rp = (const f32x4*)(logits + (size_t)(base + j) * 128);
                    process(rp[sub], rp[16 + sub], labels[base + j], base + j);
                }
            }
        }
    }

    __syncthreads();
    // Per-block partial store: every slot written, no init / no global atomics needed.
    if (tid < 3 * N_BINS)
        partial[(size_t)tid * nBlocks + blockIdx.x] = s_acc[tid];
}

__global__ __launch_bounds__(1024) void ece_final(const float* __restrict__ partial,
                                                  float* __restrict__ out,
                                                  int nBlocks, float invN) {
    __shared__ float red[3 * N_BINS];
    const int tid = threadIdx.x;
    const int w = tid >> 6, lane = tid & 63;
    for (int s = w; s < 3 * N_BINS; s += 16) {     // wave w reduces slots w, w+16, w+32
        float sum = 0.f;
        for (int i = lane; i < nBlocks; i += 64)
            sum += partial[(size_t)s * nBlocks + i];
        #pragma unroll
        for (int off = 32; off > 0; off >>= 1)
            sum += __shfl_xor(sum, off);
        if (lane == 0) red[s] = sum;
    }
    __syncthreads();
    if (tid == 0) {
        float ece = 0.f;
        #pragma unroll
        for (int b = 0; b < N_BINS; ++b) {
            if (red[b] > 0.f)
                ece += fabsf(red[N_BINS + b] - red[2 * N_BINS + b]) * invN;
        }
        out[0] = ece;
    }
}

extern "C" void kernel_launch(void* const* d_in, const int* in_sizes, int n_in,
                              void* d_out, int out_size, void* d_ws, size_t ws_size,
                              hipStream_t stream) {
    const float* logits = (const float*)d_in[0];
    const int*   labels = (const int*)d_in[1];
    float*       out    = (float*)d_out;
    float*       partial = (float*)d_ws;           // 3*N_BINS*GRID_MAIN floats = 368 KB

    const int N = in_sizes[1];                     // 1048576 rows (C fixed at 128)

    int grid = GRID_MAIN;                          // 8 blocks/CU, full residency
    const int rowsPerIter = (BLOCK >> 4) * ROWS_PER_GRP;
    if ((size_t)grid * rowsPerIter > (size_t)N)
        grid = (N + rowsPerIter - 1) / rowsPerIter;

    ece_main<<<grid, BLOCK, 0, stream>>>(logits, labels, partial, N, grid);
    ece_final<<<1, 1024, 0, stream>>>(partial, out, grid, 1.0f / (float)N);
}